// Round 18
// baseline (181.090 us; speedup 1.0000x reference)
//
#include <hip/hip_runtime.h>
#include <hip/hip_bf16.h>
#include <math.h>

#define S 2048
#define DM 2048
#define NH 16
#define DH 128
#define DR 64
#define DKV 512
#define DQ 1024
#define DQK 192  // DH + DR
#define QSCALE 0.07216878364870323f  // 1/sqrt(192)

typedef __bf16 bf16x8 __attribute__((ext_vector_type(8)));
typedef float f32x4 __attribute__((ext_vector_type(4)));
typedef unsigned short u16;

__device__ inline unsigned int pack2_bf16(float a, float b) {
    __hip_bfloat16 ha = __float2bfloat16(a);
    __hip_bfloat16 hb = __float2bfloat16(b);
    unsigned short ua = *reinterpret_cast<unsigned short*>(&ha);
    unsigned short ub = *reinterpret_cast<unsigned short*>(&hb);
    return (unsigned int)ua | ((unsigned int)ub << 16);
}
__device__ inline u16 f2bf(float v) {
    __hip_bfloat16 hb = __float2bfloat16(v);
    return *reinterpret_cast<u16*>(&hb);
}
__device__ inline void gload_lds16(const void* g, void* l) {
    __builtin_amdgcn_global_load_lds(
        (const __attribute__((address_space(1))) void*)g,
        (__attribute__((address_space(3))) void*)l, 16, 0, 0);
}

// ---------------- fused preprocessing: RoPE table + x->bf16 + 8 weight transposes ----------------
__global__ __launch_bounds__(256) void prep_kernel(
    const float* __restrict__ x,
    const float* __restrict__ W0, const float* __restrict__ W1, const float* __restrict__ W2,
    const float* __restrict__ W3, const float* __restrict__ W4, const float* __restrict__ W5,
    const float* __restrict__ W6, const float* __restrict__ W7,
    u16* __restrict__ x_bf,
    u16* __restrict__ D0, u16* __restrict__ D1, u16* __restrict__ D2, u16* __restrict__ D3,
    u16* __restrict__ D4, u16* __restrict__ D5, u16* __restrict__ D6, u16* __restrict__ D7,
    float* __restrict__ cosT, float* __restrict__ sinT) {
    __shared__ u16 tile[64][65];
    const int b = blockIdx.x;
    if (b < 3584) {
        const float* W; u16* D; int N, K, local;
        if (b < 256)       { W = W0; D = D0; N = 512;  K = 2048; local = b; }
        else if (b < 768)  { W = W1; D = D1; N = 1024; K = 2048; local = b - 256; }
        else if (b < 1280) { W = W2; D = D2; N = 1024; K = 2048; local = b - 768; }
        else if (b < 1536) { W = W3; D = D3; N = 2048; K = 512;  local = b - 1280; }
        else if (b < 1792) { W = W4; D = D4; N = 2048; K = 512;  local = b - 1536; }
        else if (b < 2304) { W = W5; D = D5; N = 2048; K = 1024; local = b - 1792; }
        else if (b < 2560) { W = W6; D = D6; N = 1024; K = 1024; local = b - 2304; }
        else               { W = W7; D = D7; N = 2048; K = 2048; local = b - 2560; }
        const int nt = N / 64;
        const int n0 = (local % nt) * 64;
        const int k0 = (local / nt) * 64;
        const int tx = threadIdx.x & 15;
        const int ty = threadIdx.x >> 4;
#pragma unroll
        for (int rep = 0; rep < 4; ++rep) {
            int kk = rep * 16 + ty;
            float4 v = *reinterpret_cast<const float4*>(&W[(size_t)(k0 + kk) * N + n0 + tx * 4]);
            tile[kk][tx * 4 + 0] = f2bf(v.x);
            tile[kk][tx * 4 + 1] = f2bf(v.y);
            tile[kk][tx * 4 + 2] = f2bf(v.z);
            tile[kk][tx * 4 + 3] = f2bf(v.w);
        }
        __syncthreads();
#pragma unroll
        for (int rep = 0; rep < 4; ++rep) {
            int nn = rep * 16 + ty;
            uint2 w;
            w.x = (unsigned int)tile[tx * 4 + 0][nn] | ((unsigned int)tile[tx * 4 + 1][nn] << 16);
            w.y = (unsigned int)tile[tx * 4 + 2][nn] | ((unsigned int)tile[tx * 4 + 3][nn] << 16);
            *reinterpret_cast<uint2*>(&D[(size_t)(n0 + nn) * K + k0 + tx * 4]) = w;
        }
    } else if (b < 7680) {
        int idx = (b - 3584) * 256 + threadIdx.x;
        float4 v = *reinterpret_cast<const float4*>(&x[(size_t)idx * 4]);
        uint2 w;
        w.x = pack2_bf16(v.x, v.y);
        w.y = pack2_bf16(v.z, v.w);
        *reinterpret_cast<uint2*>(&x_bf[(size_t)idx * 4]) = w;
    } else {
        int idx = (b - 7680) * 256 + threadIdx.x;
        int pos = idx / (DR / 2);
        int j   = idx % (DR / 2);
        float inv = __expf(-((float)(2 * j) / (float)DR) * logf(10000.0f));
        float ang = (float)pos * inv;
        cosT[idx] = cosf(ang);
        sinT[idx] = sinf(ang);
    }
}

// ---------------- bf16 MFMA GEMM core, 128x128 tile (m97 wave decomposition) ----------------
// 4 waves (2x2), wave = 64x64 via 4x4 16x16x32 MFMAs; BK=32, double-buffered 32KB LDS.
// Conflict-free slot maps (R6-verified), both-sides applied via inverse map on global src.
template <int MODE>
__device__ __forceinline__ void gemm_core(
    u16 (*lds)[8192],
    const u16* __restrict__ A, const u16* __restrict__ BT,
    void* __restrict__ P0v, void* __restrict__ P1v, void* __restrict__ P2v,
    const float* __restrict__ cosT, const float* __restrict__ sinT, int K,
    int bm, int bn) {
    const int tid  = threadIdx.x;
    const int wave = tid >> 6;
    const int lane = tid & 63;
    const int c16  = lane & 15;
    const int g    = lane >> 4;
    const int wm = (wave >> 1) * 64;
    const int wn = (wave & 1) * 64;

    f32x4 acc[4][4];
#pragma unroll
    for (int i = 0; i < 4; ++i)
#pragma unroll
        for (int j = 0; j < 4; ++j) acc[i][j] = f32x4{0.f, 0.f, 0.f, 0.f};

    auto stage = [&](int buf, int k0) {
#pragma unroll
        for (int r = 0; r < 2; ++r) {  // A: 512 chunks (128 rows x 4 kc), 2/thread
            int L = r * 256 + tid;
            int rp = L >> 3, e = L & 7, x = e ^ (rp & 7);
            int row = 2 * rp + (x >> 2), kc = x & 3;
            gload_lds16(A + (size_t)(bm + row) * K + k0 + kc * 8,
                        &lds[buf][(r * 256 + wave * 64) * 8]);
        }
#pragma unroll
        for (int r = 0; r < 2; ++r) {  // B: 512 chunks
            int L = r * 256 + tid;
            int rp = L >> 3, e = L & 7, x = e ^ (rp & 7);
            int row = 2 * rp + (x >> 2), kc = x & 3;
            gload_lds16(BT + (size_t)(bn + row) * K + k0 + kc * 8,
                        &lds[buf][4096 + (r * 256 + wave * 64) * 8]);
        }
    };

    const int NT = K / 32;
    stage(0, 0);
    __syncthreads();
    int cur = 0;
    for (int t = 0; t < NT; ++t) {
        if (t + 1 < NT) stage(cur ^ 1, (t + 1) * 32);
        bf16x8 af[4], bfr[4];
#pragma unroll
        for (int i = 0; i < 4; ++i) {
            int row  = wm + i * 16 + c16;
            int slot = ((row >> 1) << 3) + ((((row & 1) << 2) + g) ^ ((row >> 1) & 7));
            af[i] = *reinterpret_cast<const bf16x8*>(&lds[cur][slot * 8]);
        }
#pragma unroll
        for (int j = 0; j < 4; ++j) {
            int row  = wn + j * 16 + c16;
            int slot = ((row >> 1) << 3) + ((((row & 1) << 2) + g) ^ ((row >> 1) & 7));
            bfr[j] = *reinterpret_cast<const bf16x8*>(&lds[cur][4096 + slot * 8]);
        }
#pragma unroll
        for (int i = 0; i < 4; ++i)
#pragma unroll
            for (int j = 0; j < 4; ++j)
                acc[i][j] = __builtin_amdgcn_mfma_f32_16x16x32_bf16(af[i], bfr[j], acc[i][j], 0, 0, 0);
        __syncthreads();
        cur ^= 1;
    }

#pragma unroll
    for (int i = 0; i < 4; ++i)
#pragma unroll
        for (int j = 0; j < 4; ++j) {
            const int mrow = bm + wm + i * 16 + g * 4;
            const int col  = bn + wn + j * 16 + c16;
            if constexpr (MODE == 0) {
                if (col < 512) {
                    u16* down_kv = (u16*)P0v;
#pragma unroll
                    for (int r = 0; r < 4; ++r)
                        down_kv[(size_t)(mrow + r) * DKV + col] = f2bf(acc[i][j][r]);
                } else if (col < 1536) {
                    u16* down_q = (u16*)P1v;
#pragma unroll
                    for (int r = 0; r < 4; ++r)
                        down_q[(size_t)(mrow + r) * DQ + (col - 512)] = f2bf(acc[i][j][r]);
                } else {
                    u16* k_asm = (u16*)P2v;
                    const int cc = col - 1536, h = cc >> 6, rr = cc & 63, jj = rr >> 1;
#pragma unroll
                    for (int r = 0; r < 4; ++r) {
                        int pos = mrow + r;
                        float self = acc[i][j][r];
                        float vp   = __shfl_xor(self, 1);
                        float c = cosT[pos * (DR / 2) + jj];
                        float s = sinT[pos * (DR / 2) + jj];
                        float val = (rr & 1) ? (vp * s + self * c) : (self * c - vp * s);
                        k_asm[((size_t)h * S + pos) * DQK + DH + rr] = f2bf(val);
                    }
                }
            } else if constexpr (MODE == 1) {
                if (col < 2048) {
                    u16* k_asm = (u16*)P0v;
                    const int h = col >> 7, d = col & 127;
#pragma unroll
                    for (int r = 0; r < 4; ++r)
                        k_asm[((size_t)h * S + mrow + r) * DQK + d] = f2bf(acc[i][j][r]);
                } else {
                    u16* vt = (u16*)P1v;
                    const int cc = col - 2048, h = cc >> 7, d = cc & 127;
                    uint2 w;
                    w.x = pack2_bf16(acc[i][j][0], acc[i][j][1]);
                    w.y = pack2_bf16(acc[i][j][2], acc[i][j][3]);
                    *reinterpret_cast<uint2*>(&vt[((size_t)h * DH + d) * S + mrow]) = w;
                }
            } else if constexpr (MODE == 2) {
                u16* q_asm = (u16*)P0v;
                if (col < 2048) {
                    const int h = col >> 7, d = col & 127;
#pragma unroll
                    for (int r = 0; r < 4; ++r)
                        q_asm[((size_t)h * S + mrow + r) * DQK + d] = f2bf(acc[i][j][r] * QSCALE);
                } else {
                    const int cc = col - 2048, h = cc >> 6, rr = cc & 63, jj = rr >> 1;
#pragma unroll
                    for (int r = 0; r < 4; ++r) {
                        int pos = mrow + r;
                        float self = acc[i][j][r];
                        float vp   = __shfl_xor(self, 1);
                        float c = cosT[pos * (DR / 2) + jj];
                        float s = sinT[pos * (DR / 2) + jj];
                        float val = (rr & 1) ? (vp * s + self * c) : (self * c - vp * s);
                        q_asm[((size_t)h * S + pos) * DQK + DH + rr] = f2bf(val * QSCALE);
                    }
                }
            } else {  // MODE 3
                float* outp = (float*)P0v;
#pragma unroll
                for (int r = 0; r < 4; ++r)
                    outp[(size_t)(mrow + r) * DM + col] = acc[i][j][r];
            }
        }
}

// XCD-aware swizzle (T1): 1-D grid, each XCD gets a contiguous chunk of the
// m-fastest linear order (16 m-tiles). Grids %8==0 -> bijective.
template <int MODE>
__global__ __launch_bounds__(256) void gemm_fused_kernel(
    const u16* __restrict__ A, const u16* __restrict__ BT,
    void* __restrict__ P0v, void* __restrict__ P1v, void* __restrict__ P2v,
    const float* __restrict__ cosT, const float* __restrict__ sinT, int K, int nwg) {
    __shared__ u16 lds[2][8192];
    const int wgid = blockIdx.x;
    const int orig = (wgid & 7) * (nwg >> 3) + (wgid >> 3);
    const int bm = (orig & 15) * 128;   // m fastest (16 m-tiles)
    const int bn = (orig >> 4) * 128;
    gemm_core<MODE>(lds, A, BT, P0v, P1v, P2v, cosT, sinT, K, bm, bn);
}

// G2 (512 tiles) + G3 (384 tiles) merged; per-XCD proportional: 64 G2 + 48 G3 blocks
// (equal per-XCD K-work: 64*16 + 48*32 = 2560 K-step-blocks), B strips L2-resident.
__global__ __launch_bounds__(256) void gemm_g23_kernel(
    const u16* __restrict__ down_kv, const u16* __restrict__ WT2,
    const u16* __restrict__ down_q,  const u16* __restrict__ WT3,
    u16* __restrict__ k_asm, u16* __restrict__ vt, u16* __restrict__ q_asm,
    const float* __restrict__ cosT, const float* __restrict__ sinT) {
    __shared__ u16 lds[2][8192];
    const int wgid  = blockIdx.x;
    const int xcd   = wgid & 7;
    const int local = wgid >> 3;  // 0..111
    if (local < 64) {   // G2: n_idx = xcd*4 + (local>>4), m_idx = local&15
        const int bn = (xcd * 4 + (local >> 4)) * 128;
        const int bm = (local & 15) * 128;
        gemm_core<1>(lds, down_kv, WT2, k_asm, vt, nullptr, cosT, sinT, DKV, bm, bn);
    } else {            // G3: l = local-64; n_idx = xcd*3 + (l>>4), m_idx = l&15
        const int l  = local - 64;
        const int bn = (xcd * 3 + (l >> 4)) * 128;
        const int bm = (l & 15) * 128;
        gemm_core<2>(lds, down_q, WT3, q_asm, nullptr, nullptr, cosT, sinT, DQ, bm, bn);
    }
}

// ---------------- MFMA flash attention v10 (R14-verified, 54us): 8 waves, intra-block split-KV ----------------
__global__ __launch_bounds__(512) void attn_mfma_kernel(const u16* __restrict__ q,   // (NH,S,192) pre-scaled
                                                        const u16* __restrict__ k,   // (NH,S,192)
                                                        const u16* __restrict__ vt,  // (NH,DH,S)
                                                        u16* __restrict__ outp) {    // (S, NH*DH) bf16
    const int wgid = blockIdx.x;        // 0..255
    const int xcd  = wgid & 7;
    const int i    = wgid >> 3;         // 0..31 per xcd
    const int h    = xcd * 2 + (i & 1); // head pinned to XCD
    const int pr   = i >> 1;            // 0..15
    const int qtA  = 31 - pr;
    const int qtB  = pr;

    const int tid  = threadIdx.x;       // 0..511
    const int wave = tid >> 6;          // 0..7
    const int grp  = wave >> 2;         // 0: even tiles, 1: odd tiles
    const int w4   = wave & 3;          // q-row group within grp
    const int lane = tid & 63;
    const int col  = lane & 15;
    const int g    = lane >> 4;

    __shared__ __align__(16) char arena[92160];
    u16* KtG = (u16*)(arena + (grp ? 24576 : 0));
    u16* VtG = (u16*)(arena + 49152 + (grp ? 16384 : 0));
    u16* p_my = (u16*)(arena + 81920 + wave * 1024);
    float2* ml = (float2*)(arena + 90112);
    f32x4* cmb = (f32x4*)(arena);

    const int r7  = col & 7;
    const int pv7 = (col >> 1) & 7;
    const int pvb = (col & 1) << 2;

    auto stage_pair = [&](int buf, int j0E) {
#pragma unroll
        for (int c = 0; c < 5; ++c) {
            int idx = wave + c * 8;
            if (idx < 12) {
                int L = idx * 64 + lane;
                int row = L / 24, rem = L - row * 24;
                int ch  = ((rem >> 3) << 3) + ((rem & 7) ^ (row & 7));
                gload_lds16(k + ((size_t)h * S + j0E + row) * DQK + ch * 8,
                            (u16*)(arena) + buf * 6144 + idx * 512);
            } else if (idx < 20) {
                int s2 = idx - 12;
                int L = s2 * 64 + lane;
                int rp = L >> 3, x = (L & 7) ^ (rp & 7);
                int d  = 2 * rp + (x >> 2), kc = x & 3;
                gload_lds16(vt + ((size_t)h * DH + d) * S + j0E + kc * 8,
                            (u16*)(arena + 49152) + buf * 4096 + s2 * 512);
            } else if (idx < 32) {
                int s2 = idx - 20;
                int L = s2 * 64 + lane;
                int row = L / 24, rem = L - row * 24;
                int ch  = ((rem >> 3) << 3) + ((rem & 7) ^ (row & 7));
                gload_lds16(k + ((size_t)h * S + j0E + 32 + row) * DQK + ch * 8,
                            (u16*)(arena + 24576) + buf * 6144 + s2 * 512);
            } else {
                int s2 = idx - 32;
                int L = s2 * 64 + lane;
                int rp = L >> 3, x = (L & 7) ^ (rp & 7);
                int d  = 2 * rp + (x >> 2), kc = x & 3;
                gload_lds16(vt + ((size_t)h * DH + d) * S + j0E + 32 + kc * 8,
                            (u16*)(arena + 65536) + buf * 4096 + s2 * 512);
            }
        }
    };

    auto phase = [&](int qt) {
        const int q0 = qt * 64;
        const int qw = q0 + w4 * 16;
        const int I  = qt + 1;

        bf16x8 qf[6];
        const u16* qbase = q + ((size_t)h * S + qw + col) * DQK + g * 8;
#pragma unroll
        for (int c = 0; c < 6; ++c) qf[c] = *reinterpret_cast<const bf16x8*>(qbase + c * 32);

        f32x4 acc[8];
#pragma unroll
        for (int c = 0; c < 8; ++c) acc[c] = f32x4{0.f, 0.f, 0.f, 0.f};
        float m_run = -1e30f, l_run = 0.f;

        stage_pair(0, 0);
        __syncthreads();
        for (int tp = 0; tp < I; ++tp) {
            if (tp + 1 < I) stage_pair((tp + 1) & 1, (tp + 1) * 64);
            const int buf = tp & 1;
            const int j0  = tp * 64 + grp * 32;
            const u16* Kc = KtG + buf * 6144;
            const u16* Vc = VtG + buf * 4096;

            f32x4 st[2];
            st[0] = f32x4{0.f, 0.f, 0.f, 0.f};
            st[1] = f32x4{0.f, 0.f, 0.f, 0.f};
#pragma unroll
            for (int tt = 0; tt < 2; ++tt) {
                int rb = (16 * tt + col) * 24;
#pragma unroll
                for (int c = 0; c < 6; ++c) {
                    int ch   = g + 4 * c;
                    int slot = rb + ((ch >> 3) << 3) + ((ch & 7) ^ r7);
                    bf16x8 kf = *reinterpret_cast<const bf16x8*>(Kc + slot * 8);
                    st[tt] = __builtin_amdgcn_mfma_f32_16x16x32_bf16(kf, qf[c], st[tt], 0, 0, 0);
                }
            }
#pragma unroll
            for (int tt = 0; tt < 2; ++tt) {
                if (j0 + 16 * tt + 15 > qw) {
#pragma unroll
                    for (int r = 0; r < 4; ++r) {
                        int key = j0 + 16 * tt + 4 * g + r;
                        st[tt][r] = (key > qw + col) ? -1e30f : st[tt][r];
                    }
                }
            }
            float tmax = fmaxf(fmaxf(fmaxf(st[0][0], st[0][1]), fmaxf(st[0][2], st[0][3])),
                               fmaxf(fmaxf(st[1][0], st[1][1]), fmaxf(st[1][2], st[1][3])));
            tmax = fmaxf(tmax, __shfl_xor(tmax, 16));
            tmax = fmaxf(tmax, __shfl_xor(tmax, 32));
            float m_new;
            if (__all(tmax - m_run <= 8.0f)) {
                m_new = m_run;
            } else {
                m_new = fmaxf(m_run, tmax);
                float r_scale = __expf(m_run - m_new);
                l_run *= r_scale;
#pragma unroll
                for (int c = 0; c < 8; ++c) {
                    acc[c][0] *= r_scale; acc[c][1] *= r_scale;
                    acc[c][2] *= r_scale; acc[c][3] *= r_scale;
                }
                m_run = m_new;
            }
            float m_sub = (m_new <= -1e29f) ? 0.f : m_new;
            float p[8];
            float psum = 0.f;
#pragma unroll
            for (int tt = 0; tt < 2; ++tt)
#pragma unroll
                for (int r = 0; r < 4; ++r) {
                    float pv = __expf(st[tt][r] - m_sub);
                    p[tt * 4 + r] = pv;
                    psum += pv;
                }
            psum += __shfl_xor(psum, 16);
            psum += __shfl_xor(psum, 32);
            l_run += psum;
#pragma unroll
            for (int tt = 0; tt < 2; ++tt) {
                uint2 w;
                w.x = pack2_bf16(p[tt * 4 + 0], p[tt * 4 + 1]);
                w.y = pack2_bf16(p[tt * 4 + 2], p[tt * 4 + 3]);
                int ch   = 2 * tt + (g >> 1);
                int slot = ((col >> 1) << 3) + ((pvb + ch) ^ pv7);
                *reinterpret_cast<uint2*>(p_my + slot * 8 + (g & 1) * 4) = w;
            }
            {
                int slot = ((col >> 1) << 3) + ((pvb + g) ^ pv7);
                bf16x8 pf = *reinterpret_cast<const bf16x8*>(p_my + slot * 8);
#pragma unroll
                for (int c = 0; c < 8; ++c) {
                    int d  = 16 * c + col;
                    int vs = ((d >> 1) << 3) + ((pvb + g) ^ pv7);
                    bf16x8 vf = *reinterpret_cast<const bf16x8*>(Vc + vs * 8);
                    acc[c] = __builtin_amdgcn_mfma_f32_16x16x32_bf16(vf, pf, acc[c], 0, 0, 0);
                }
            }
            __syncthreads();
        }

        if (grp == 1) {
#pragma unroll
            for (int c = 0; c < 8; ++c) cmb[(w4 * 8 + c) * 64 + lane] = acc[c];
            ml[w4 * 64 + lane] = make_float2(m_run, l_run);
        }
        __syncthreads();
        if (grp == 0) {
            float2 mlB = ml[w4 * 64 + lane];
            float m = fmaxf(m_run, mlB.x);
            float sA = __expf(m_run - m);
            float sB = __expf(mlB.x - m);
            float l  = l_run * sA + mlB.y * sB;
            float inv_l = 1.0f / l;
#pragma unroll
            for (int c = 0; c < 8; ++c) {
                f32x4 aB = cmb[(w4 * 8 + c) * 64 + lane];
#pragma unroll
                for (int r = 0; r < 4; ++r) {
                    float v = (acc[c][r] * sA + aB[r] * sB) * inv_l;
                    outp[(size_t)(qw + col) * (NH * DH) + h * DH + 16 * c + 4 * g + r] = f2bf(v);
                }
            }
        }
        __syncthreads();
    };

    phase(qtA);
    phase(qtB);
}

// ---------------- launch ----------------
extern "C" void kernel_launch(void* const* d_in, const int* in_sizes, int n_in,
                              void* d_out, int out_size, void* d_ws, size_t ws_size,
                              hipStream_t stream) {
    const float* x         = (const float*)d_in[0];
    const float* W_kv_down = (const float*)d_in[2];
    const float* W_k_up    = (const float*)d_in[3];
    const float* W_v_up    = (const float*)d_in[4];
    const float* W_q_down  = (const float*)d_in[5];
    const float* W_q_up    = (const float*)d_in[6];
    const float* W_q_rope  = (const float*)d_in[7];
    const float* W_k_rope  = (const float*)d_in[8];
    const float* W_out     = (const float*)d_in[9];
    float* out = (float*)d_out;

    float* w = (float*)d_ws;
    float* cosT = w;
    float* sinT = w + (size_t)S * (DR / 2);
    u16* b = (u16*)(w + 2 * (size_t)S * (DR / 2));
    size_t off = 0;
    u16* x_bf    = b + off; off += (size_t)S * DM;
    u16* WT1     = b + off; off += (size_t)2560 * DM;
    u16* WT2     = b + off; off += (size_t)4096 * DKV;
    u16* WT3     = b + off; off += (size_t)3072 * DQ;
    u16* WT4     = b + off; off += (size_t)DM * DM;
    u16* down_kv = b + off; off += (size_t)S * DKV;
    u16* down_q  = b + off; off += (size_t)S * DQ;
    u16* q_asm   = b + off; off += (size_t)NH * S * DQK;
    u16* k_asm   = b + off; off += (size_t)NH * S * DQK;
    u16* vt      = b + off; off += (size_t)NH * DH * S;
    u16* attn_bf = b + off; off += (size_t)S * NH * DH;

    prep_kernel<<<7936, 256, 0, stream>>>(
        x, W_kv_down, W_q_down, W_k_rope, W_k_up, W_v_up, W_q_up, W_q_rope, W_out,
        x_bf,
        WT1, WT1 + (size_t)512 * DM, WT1 + (size_t)1536 * DM,
        WT2, WT2 + (size_t)2048 * DKV,
        WT3, WT3 + (size_t)2048 * DQ, WT4,
        cosT, sinT);

    // G1: x @ [W_kv_down | W_q_down | W_k_rope], N=2560 (20 n-tiles), M=2048 (16 m-tiles)
    gemm_fused_kernel<0><<<320, 256, 0, stream>>>(
        x_bf, WT1, down_kv, down_q, k_asm, cosT, sinT, DM, 320);

    // G2+G3 merged: 8 XCDs x (64 G2 + 48 G3) = 896 blocks
    gemm_g23_kernel<<<896, 256, 0, stream>>>(
        down_kv, WT2, down_q, WT3, k_asm, vt, q_asm, cosT, sinT);

    attn_mfma_kernel<<<256, 512, 0, stream>>>(q_asm, k_asm, vt, attn_bf);

    // G4: attn_out @ W_out, N=2048 (16 n-tiles), M=2048 (16 m-tiles)
    gemm_fused_kernel<3><<<256, 256, 0, stream>>>(
        attn_bf, WT4, out, nullptr, nullptr, cosT, sinT, DM, 256);
}

// Round 19
// 180.781 us; speedup vs baseline: 1.0017x; 1.0017x over previous
//
#include <hip/hip_runtime.h>
#include <hip/hip_bf16.h>
#include <math.h>

#define S 2048
#define DM 2048
#define NH 16
#define DH 128
#define DR 64
#define DKV 512
#define DQ 1024
#define DQK 192  // DH + DR
#define QSCALE 0.07216878364870323f  // 1/sqrt(192)

typedef __bf16 bf16x8 __attribute__((ext_vector_type(8)));
typedef float f32x4 __attribute__((ext_vector_type(4)));
typedef unsigned short u16;

__device__ inline unsigned int pack2_bf16(float a, float b) {
    __hip_bfloat16 ha = __float2bfloat16(a);
    __hip_bfloat16 hb = __float2bfloat16(b);
    unsigned short ua = *reinterpret_cast<unsigned short*>(&ha);
    unsigned short ub = *reinterpret_cast<unsigned short*>(&hb);
    return (unsigned int)ua | ((unsigned int)ub << 16);
}
__device__ inline u16 f2bf(float v) {
    __hip_bfloat16 hb = __float2bfloat16(v);
    return *reinterpret_cast<u16*>(&hb);
}
__device__ inline void gload_lds16(const void* g, void* l) {
    __builtin_amdgcn_global_load_lds(
        (const __attribute__((address_space(1))) void*)g,
        (__attribute__((address_space(3))) void*)l, 16, 0, 0);
}

// ---------------- fused preprocessing: RoPE table + x->bf16 + 8 weight transposes ----------------
__global__ __launch_bounds__(256) void prep_kernel(
    const float* __restrict__ x,
    const float* __restrict__ W0, const float* __restrict__ W1, const float* __restrict__ W2,
    const float* __restrict__ W3, const float* __restrict__ W4, const float* __restrict__ W5,
    const float* __restrict__ W6, const float* __restrict__ W7,
    u16* __restrict__ x_bf,
    u16* __restrict__ D0, u16* __restrict__ D1, u16* __restrict__ D2, u16* __restrict__ D3,
    u16* __restrict__ D4, u16* __restrict__ D5, u16* __restrict__ D6, u16* __restrict__ D7,
    float* __restrict__ cosT, float* __restrict__ sinT) {
    __shared__ u16 tile[64][65];
    const int b = blockIdx.x;
    if (b < 3584) {
        const float* W; u16* D; int N, K, local;
        if (b < 256)       { W = W0; D = D0; N = 512;  K = 2048; local = b; }
        else if (b < 768)  { W = W1; D = D1; N = 1024; K = 2048; local = b - 256; }
        else if (b < 1280) { W = W2; D = D2; N = 1024; K = 2048; local = b - 768; }
        else if (b < 1536) { W = W3; D = D3; N = 2048; K = 512;  local = b - 1280; }
        else if (b < 1792) { W = W4; D = D4; N = 2048; K = 512;  local = b - 1536; }
        else if (b < 2304) { W = W5; D = D5; N = 2048; K = 1024; local = b - 1792; }
        else if (b < 2560) { W = W6; D = D6; N = 1024; K = 1024; local = b - 2304; }
        else               { W = W7; D = D7; N = 2048; K = 2048; local = b - 2560; }
        const int nt = N / 64;
        const int n0 = (local % nt) * 64;
        const int k0 = (local / nt) * 64;
        const int tx = threadIdx.x & 15;
        const int ty = threadIdx.x >> 4;
#pragma unroll
        for (int rep = 0; rep < 4; ++rep) {
            int kk = rep * 16 + ty;
            float4 v = *reinterpret_cast<const float4*>(&W[(size_t)(k0 + kk) * N + n0 + tx * 4]);
            tile[kk][tx * 4 + 0] = f2bf(v.x);
            tile[kk][tx * 4 + 1] = f2bf(v.y);
            tile[kk][tx * 4 + 2] = f2bf(v.z);
            tile[kk][tx * 4 + 3] = f2bf(v.w);
        }
        __syncthreads();
#pragma unroll
        for (int rep = 0; rep < 4; ++rep) {
            int nn = rep * 16 + ty;
            uint2 w;
            w.x = (unsigned int)tile[tx * 4 + 0][nn] | ((unsigned int)tile[tx * 4 + 1][nn] << 16);
            w.y = (unsigned int)tile[tx * 4 + 2][nn] | ((unsigned int)tile[tx * 4 + 3][nn] << 16);
            *reinterpret_cast<uint2*>(&D[(size_t)(n0 + nn) * K + k0 + tx * 4]) = w;
        }
    } else if (b < 7680) {
        int idx = (b - 3584) * 256 + threadIdx.x;
        float4 v = *reinterpret_cast<const float4*>(&x[(size_t)idx * 4]);
        uint2 w;
        w.x = pack2_bf16(v.x, v.y);
        w.y = pack2_bf16(v.z, v.w);
        *reinterpret_cast<uint2*>(&x_bf[(size_t)idx * 4]) = w;
    } else {
        int idx = (b - 7680) * 256 + threadIdx.x;
        int pos = idx / (DR / 2);
        int j   = idx % (DR / 2);
        float inv = __expf(-((float)(2 * j) / (float)DR) * logf(10000.0f));
        float ang = (float)pos * inv;
        cosT[idx] = cosf(ang);
        sinT[idx] = sinf(ang);
    }
}

// ---------------- bf16 MFMA GEMM core with fused epilogues (R11/R17-verified structure) ----------------
template <int MODE>
__device__ __forceinline__ void gemm_core(
    u16 (*lds)[6144],
    const u16* __restrict__ A, const u16* __restrict__ BT,
    void* __restrict__ P0v, void* __restrict__ P1v, void* __restrict__ P2v,
    const float* __restrict__ cosT, const float* __restrict__ sinT, int K,
    int bm, int bn) {
    const int tid  = threadIdx.x;
    const int wave = tid >> 6;
    const int lane = tid & 63;
    const int c16  = lane & 15;
    const int g    = lane >> 4;
    const int wm = (wave >> 1) * 32;
    const int wn = (wave & 1) * 64;

    f32x4 acc[2][4];
#pragma unroll
    for (int i = 0; i < 2; ++i)
#pragma unroll
        for (int j = 0; j < 4; ++j) acc[i][j] = f32x4{0.f, 0.f, 0.f, 0.f};

    auto stage = [&](int buf, int k0) {
        {
            int L = tid;
            int rp = L >> 3, e = L & 7, x = e ^ (rp & 7);
            int row = 2 * rp + (x >> 2), kc = x & 3;
            gload_lds16(A + (size_t)(bm + row) * K + k0 + kc * 8, &lds[buf][wave * 512]);
        }
#pragma unroll
        for (int r = 0; r < 2; ++r) {
            int L = r * 256 + tid;
            int rp = L >> 3, e = L & 7, x = e ^ (rp & 7);
            int row = 2 * rp + (x >> 2), kc = x & 3;
            gload_lds16(BT + (size_t)(bn + row) * K + k0 + kc * 8,
                        &lds[buf][2048 + (r * 256 + wave * 64) * 8]);
        }
    };

    const int NT = K / 32;
    stage(0, 0);
    __syncthreads();
    int cur = 0;
    for (int t = 0; t < NT; ++t) {
        if (t + 1 < NT) stage(cur ^ 1, (t + 1) * 32);
        bf16x8 af[2], bfr[4];
#pragma unroll
        for (int i = 0; i < 2; ++i) {
            int row  = wm + i * 16 + c16;
            int slot = ((row >> 1) << 3) + ((((row & 1) << 2) + g) ^ ((row >> 1) & 7));
            af[i] = *reinterpret_cast<const bf16x8*>(&lds[cur][slot * 8]);
        }
#pragma unroll
        for (int j = 0; j < 4; ++j) {
            int row  = wn + j * 16 + c16;
            int slot = ((row >> 1) << 3) + ((((row & 1) << 2) + g) ^ ((row >> 1) & 7));
            bfr[j] = *reinterpret_cast<const bf16x8*>(&lds[cur][2048 + slot * 8]);
        }
#pragma unroll
        for (int i = 0; i < 2; ++i)
#pragma unroll
            for (int j = 0; j < 4; ++j)
                acc[i][j] = __builtin_amdgcn_mfma_f32_16x16x32_bf16(af[i], bfr[j], acc[i][j], 0, 0, 0);
        __syncthreads();
        cur ^= 1;
    }

#pragma unroll
    for (int i = 0; i < 2; ++i)
#pragma unroll
        for (int j = 0; j < 4; ++j) {
            const int mrow = bm + wm + i * 16 + g * 4;
            const int col  = bn + wn + j * 16 + c16;
            if constexpr (MODE == 0) {
                if (col < 512) {
                    u16* down_kv = (u16*)P0v;
#pragma unroll
                    for (int r = 0; r < 4; ++r)
                        down_kv[(size_t)(mrow + r) * DKV + col] = f2bf(acc[i][j][r]);
                } else if (col < 1536) {
                    u16* down_q = (u16*)P1v;
#pragma unroll
                    for (int r = 0; r < 4; ++r)
                        down_q[(size_t)(mrow + r) * DQ + (col - 512)] = f2bf(acc[i][j][r]);
                } else {
                    u16* k_asm = (u16*)P2v;
                    const int cc = col - 1536, h = cc >> 6, rr = cc & 63, jj = rr >> 1;
#pragma unroll
                    for (int r = 0; r < 4; ++r) {
                        int pos = mrow + r;
                        float self = acc[i][j][r];
                        float vp   = __shfl_xor(self, 1);
                        float c = cosT[pos * (DR / 2) + jj];
                        float s = sinT[pos * (DR / 2) + jj];
                        float val = (rr & 1) ? (vp * s + self * c) : (self * c - vp * s);
                        k_asm[((size_t)h * S + pos) * DQK + DH + rr] = f2bf(val);
                    }
                }
            } else if constexpr (MODE == 1) {
                if (col < 2048) {
                    u16* k_asm = (u16*)P0v;
                    const int h = col >> 7, d = col & 127;
#pragma unroll
                    for (int r = 0; r < 4; ++r)
                        k_asm[((size_t)h * S + mrow + r) * DQK + d] = f2bf(acc[i][j][r]);
                } else {
                    u16* vt = (u16*)P1v;
                    const int cc = col - 2048, h = cc >> 7, d = cc & 127;
                    uint2 w;
                    w.x = pack2_bf16(acc[i][j][0], acc[i][j][1]);
                    w.y = pack2_bf16(acc[i][j][2], acc[i][j][3]);
                    *reinterpret_cast<uint2*>(&vt[((size_t)h * DH + d) * S + mrow]) = w;
                }
            } else if constexpr (MODE == 2) {
                u16* q_asm = (u16*)P0v;
                if (col < 2048) {
                    const int h = col >> 7, d = col & 127;
#pragma unroll
                    for (int r = 0; r < 4; ++r)
                        q_asm[((size_t)h * S + mrow + r) * DQK + d] = f2bf(acc[i][j][r] * QSCALE);
                } else {
                    const int cc = col - 2048, h = cc >> 6, rr = cc & 63, jj = rr >> 1;
#pragma unroll
                    for (int r = 0; r < 4; ++r) {
                        int pos = mrow + r;
                        float self = acc[i][j][r];
                        float vp   = __shfl_xor(self, 1);
                        float c = cosT[pos * (DR / 2) + jj];
                        float s = sinT[pos * (DR / 2) + jj];
                        float val = (rr & 1) ? (vp * s + self * c) : (self * c - vp * s);
                        q_asm[((size_t)h * S + pos) * DQK + DH + rr] = f2bf(val * QSCALE);
                    }
                }
            } else {  // MODE 3
                float* outp = (float*)P0v;
#pragma unroll
                for (int r = 0; r < 4; ++r)
                    outp[(size_t)(mrow + r) * DM + col] = acc[i][j][r];
            }
        }
}

// XCD-aware swizzle (T1): 1-D grid, xcd = wgid&7 gets a contiguous chunk of the
// m-fastest linear order -> per-XCD B-panel strip L2-resident. Grids %8==0 -> bijective.
template <int MODE>
__global__ __launch_bounds__(256) void gemm_fused_kernel(
    const u16* __restrict__ A, const u16* __restrict__ BT,
    void* __restrict__ P0v, void* __restrict__ P1v, void* __restrict__ P2v,
    const float* __restrict__ cosT, const float* __restrict__ sinT, int K, int nwg) {
    __shared__ u16 lds[2][6144];
    const int wgid = blockIdx.x;
    const int orig = (wgid & 7) * (nwg >> 3) + (wgid >> 3);
    const int bm = (orig & 31) * 64;   // m fastest (32 m-tiles)
    const int bn = (orig >> 5) * 128;
    gemm_core<MODE>(lds, A, BT, P0v, P1v, P2v, cosT, sinT, K, bm, bn);
}

// G2 (1024 tiles) + G3 (768 tiles) merged, XCD-swizzled with PROPORTIONAL per-XCD split:
// each XCD gets 128 G2 blocks (4 n-tiles x 32 m) + 96 G3 blocks (3 n-tiles x 32 m).
__global__ __launch_bounds__(256) void gemm_g23_kernel(
    const u16* __restrict__ down_kv, const u16* __restrict__ WT2,
    const u16* __restrict__ down_q,  const u16* __restrict__ WT3,
    u16* __restrict__ k_asm, u16* __restrict__ vt, u16* __restrict__ q_asm,
    const float* __restrict__ cosT, const float* __restrict__ sinT) {
    __shared__ u16 lds[2][6144];
    const int wgid  = blockIdx.x;
    const int xcd   = wgid & 7;
    const int local = wgid >> 3;  // 0..223
    if (local < 128) {
        const int bn = (xcd * 4 + (local >> 5)) * 128;
        const int bm = (local & 31) * 64;
        gemm_core<1>(lds, down_kv, WT2, k_asm, vt, nullptr, cosT, sinT, DKV, bm, bn);
    } else {
        const int l  = local - 128;
        const int bn = (xcd * 3 + (l >> 5)) * 128;
        const int bm = (l & 31) * 64;
        gemm_core<2>(lds, down_q, WT3, q_asm, nullptr, nullptr, cosT, sinT, DQ, bm, bn);
    }
}

// ---------------- MFMA flash attention v10 + T5 setprio: 8 waves, intra-block split-KV ----------------
__global__ __launch_bounds__(512) void attn_mfma_kernel(const u16* __restrict__ q,   // (NH,S,192) pre-scaled
                                                        const u16* __restrict__ k,   // (NH,S,192)
                                                        const u16* __restrict__ vt,  // (NH,DH,S)
                                                        u16* __restrict__ outp) {    // (S, NH*DH) bf16
    const int wgid = blockIdx.x;        // 0..255
    const int xcd  = wgid & 7;
    const int i    = wgid >> 3;         // 0..31 per xcd
    const int h    = xcd * 2 + (i & 1); // head pinned to XCD
    const int pr   = i >> 1;            // 0..15
    const int qtA  = 31 - pr;
    const int qtB  = pr;

    const int tid  = threadIdx.x;       // 0..511
    const int wave = tid >> 6;          // 0..7
    const int grp  = wave >> 2;         // 0: even tiles, 1: odd tiles
    const int w4   = wave & 3;          // q-row group within grp
    const int lane = tid & 63;
    const int col  = lane & 15;
    const int g    = lane >> 4;

    __shared__ __align__(16) char arena[92160];
    u16* KtG = (u16*)(arena + (grp ? 24576 : 0));
    u16* VtG = (u16*)(arena + 49152 + (grp ? 16384 : 0));
    u16* p_my = (u16*)(arena + 81920 + wave * 1024);
    float2* ml = (float2*)(arena + 90112);
    f32x4* cmb = (f32x4*)(arena);

    const int r7  = col & 7;
    const int pv7 = (col >> 1) & 7;
    const int pvb = (col & 1) << 2;

    auto stage_pair = [&](int buf, int j0E) {
#pragma unroll
        for (int c = 0; c < 5; ++c) {
            int idx = wave + c * 8;
            if (idx < 12) {
                int L = idx * 64 + lane;
                int row = L / 24, rem = L - row * 24;
                int ch  = ((rem >> 3) << 3) + ((rem & 7) ^ (row & 7));
                gload_lds16(k + ((size_t)h * S + j0E + row) * DQK + ch * 8,
                            (u16*)(arena) + buf * 6144 + idx * 512);
            } else if (idx < 20) {
                int s2 = idx - 12;
                int L = s2 * 64 + lane;
                int rp = L >> 3, x = (L & 7) ^ (rp & 7);
                int d  = 2 * rp + (x >> 2), kc = x & 3;
                gload_lds16(vt + ((size_t)h * DH + d) * S + j0E + kc * 8,
                            (u16*)(arena + 49152) + buf * 4096 + s2 * 512);
            } else if (idx < 32) {
                int s2 = idx - 20;
                int L = s2 * 64 + lane;
                int row = L / 24, rem = L - row * 24;
                int ch  = ((rem >> 3) << 3) + ((rem & 7) ^ (row & 7));
                gload_lds16(k + ((size_t)h * S + j0E + 32 + row) * DQK + ch * 8,
                            (u16*)(arena + 24576) + buf * 6144 + s2 * 512);
            } else {
                int s2 = idx - 32;
                int L = s2 * 64 + lane;
                int rp = L >> 3, x = (L & 7) ^ (rp & 7);
                int d  = 2 * rp + (x >> 2), kc = x & 3;
                gload_lds16(vt + ((size_t)h * DH + d) * S + j0E + 32 + kc * 8,
                            (u16*)(arena + 65536) + buf * 4096 + s2 * 512);
            }
        }
    };

    auto phase = [&](int qt) {
        const int q0 = qt * 64;
        const int qw = q0 + w4 * 16;
        const int I  = qt + 1;

        bf16x8 qf[6];
        const u16* qbase = q + ((size_t)h * S + qw + col) * DQK + g * 8;
#pragma unroll
        for (int c = 0; c < 6; ++c) qf[c] = *reinterpret_cast<const bf16x8*>(qbase + c * 32);

        f32x4 acc[8];
#pragma unroll
        for (int c = 0; c < 8; ++c) acc[c] = f32x4{0.f, 0.f, 0.f, 0.f};
        float m_run = -1e30f, l_run = 0.f;

        stage_pair(0, 0);
        __syncthreads();
        for (int tp = 0; tp < I; ++tp) {
            if (tp + 1 < I) stage_pair((tp + 1) & 1, (tp + 1) * 64);
            const int buf = tp & 1;
            const int j0  = tp * 64 + grp * 32;
            const u16* Kc = KtG + buf * 6144;
            const u16* Vc = VtG + buf * 4096;

            f32x4 st[2];
            st[0] = f32x4{0.f, 0.f, 0.f, 0.f};
            st[1] = f32x4{0.f, 0.f, 0.f, 0.f};
            __builtin_amdgcn_s_setprio(1);  // T5: favor this wave's MFMA cluster
#pragma unroll
            for (int tt = 0; tt < 2; ++tt) {
                int rb = (16 * tt + col) * 24;
#pragma unroll
                for (int c = 0; c < 6; ++c) {
                    int ch   = g + 4 * c;
                    int slot = rb + ((ch >> 3) << 3) + ((ch & 7) ^ r7);
                    bf16x8 kf = *reinterpret_cast<const bf16x8*>(&Kc[slot * 8]);
                    st[tt] = __builtin_amdgcn_mfma_f32_16x16x32_bf16(kf, qf[c], st[tt], 0, 0, 0);
                }
            }
            __builtin_amdgcn_s_setprio(0);
#pragma unroll
            for (int tt = 0; tt < 2; ++tt) {
                if (j0 + 16 * tt + 15 > qw) {
#pragma unroll
                    for (int r = 0; r < 4; ++r) {
                        int key = j0 + 16 * tt + 4 * g + r;
                        st[tt][r] = (key > qw + col) ? -1e30f : st[tt][r];
                    }
                }
            }
            float tmax = fmaxf(fmaxf(fmaxf(st[0][0], st[0][1]), fmaxf(st[0][2], st[0][3])),
                               fmaxf(fmaxf(st[1][0], st[1][1]), fmaxf(st[1][2], st[1][3])));
            tmax = fmaxf(tmax, __shfl_xor(tmax, 16));
            tmax = fmaxf(tmax, __shfl_xor(tmax, 32));
            float m_new;
            if (__all(tmax - m_run <= 8.0f)) {
                m_new = m_run;
            } else {
                m_new = fmaxf(m_run, tmax);
                float r_scale = __expf(m_run - m_new);
                l_run *= r_scale;
#pragma unroll
                for (int c = 0; c < 8; ++c) {
                    acc[c][0] *= r_scale; acc[c][1] *= r_scale;
                    acc[c][2] *= r_scale; acc[c][3] *= r_scale;
                }
                m_run = m_new;
            }
            float m_sub = (m_new <= -1e29f) ? 0.f : m_new;
            float p[8];
            float psum = 0.f;
#pragma unroll
            for (int tt = 0; tt < 2; ++tt)
#pragma unroll
                for (int r = 0; r < 4; ++r) {
                    float pv = __expf(st[tt][r] - m_sub);
                    p[tt * 4 + r] = pv;
                    psum += pv;
                }
            psum += __shfl_xor(psum, 16);
            psum += __shfl_xor(psum, 32);
            l_run += psum;
#pragma unroll
            for (int tt = 0; tt < 2; ++tt) {
                uint2 w;
                w.x = pack2_bf16(p[tt * 4 + 0], p[tt * 4 + 1]);
                w.y = pack2_bf16(p[tt * 4 + 2], p[tt * 4 + 3]);
                int ch   = 2 * tt + (g >> 1);
                int slot = ((col >> 1) << 3) + ((pvb + ch) ^ pv7);
                *reinterpret_cast<uint2*>(p_my + slot * 8 + (g & 1) * 4) = w;
            }
            {
                int slot = ((col >> 1) << 3) + ((pvb + g) ^ pv7);
                bf16x8 pf = *reinterpret_cast<const bf16x8*>(p_my + slot * 8);
                __builtin_amdgcn_s_setprio(1);  // T5: PV cluster
#pragma unroll
                for (int c = 0; c < 8; ++c) {
                    int d  = 16 * c + col;
                    int vs = ((d >> 1) << 3) + ((pvb + g) ^ pv7);
                    bf16x8 vf = *reinterpret_cast<const bf16x8*>(&Vc[vs * 8]);
                    acc[c] = __builtin_amdgcn_mfma_f32_16x16x32_bf16(vf, pf, acc[c], 0, 0, 0);
                }
                __builtin_amdgcn_s_setprio(0);
            }
            __syncthreads();
        }

        if (grp == 1) {
#pragma unroll
            for (int c = 0; c < 8; ++c) cmb[(w4 * 8 + c) * 64 + lane] = acc[c];
            ml[w4 * 64 + lane] = make_float2(m_run, l_run);
        }
        __syncthreads();
        if (grp == 0) {
            float2 mlB = ml[w4 * 64 + lane];
            float m = fmaxf(m_run, mlB.x);
            float sA = __expf(m_run - m);
            float sB = __expf(mlB.x - m);
            float l  = l_run * sA + mlB.y * sB;
            float inv_l = 1.0f / l;
#pragma unroll
            for (int c = 0; c < 8; ++c) {
                f32x4 aB = cmb[(w4 * 8 + c) * 64 + lane];
#pragma unroll
                for (int r = 0; r < 4; ++r) {
                    float v = (acc[c][r] * sA + aB[r] * sB) * inv_l;
                    outp[(size_t)(qw + col) * (NH * DH) + h * DH + 16 * c + 4 * g + r] = f2bf(v);
                }
            }
        }
        __syncthreads();
    };

    phase(qtA);
    phase(qtB);
}

// ---------------- launch ----------------
extern "C" void kernel_launch(void* const* d_in, const int* in_sizes, int n_in,
                              void* d_out, int out_size, void* d_ws, size_t ws_size,
                              hipStream_t stream) {
    const float* x         = (const float*)d_in[0];
    const float* W_kv_down = (const float*)d_in[2];
    const float* W_k_up    = (const float*)d_in[3];
    const float* W_v_up    = (const float*)d_in[4];
    const float* W_q_down  = (const float*)d_in[5];
    const float* W_q_up    = (const float*)d_in[6];
    const float* W_q_rope  = (const float*)d_in[7];
    const float* W_k_rope  = (const float*)d_in[8];
    const float* W_out     = (const float*)d_in[9];
    float* out = (float*)d_out;

    float* w = (float*)d_ws;
    float* cosT = w;
    float* sinT = w + (size_t)S * (DR / 2);
    u16* b = (u16*)(w + 2 * (size_t)S * (DR / 2));
    size_t off = 0;
    u16* x_bf    = b + off; off += (size_t)S * DM;
    u16* WT1     = b + off; off += (size_t)2560 * DM;
    u16* WT2     = b + off; off += (size_t)4096 * DKV;
    u16* WT3     = b + off; off += (size_t)3072 * DQ;
    u16* WT4     = b + off; off += (size_t)DM * DM;
    u16* down_kv = b + off; off += (size_t)S * DKV;
    u16* down_q  = b + off; off += (size_t)S * DQ;
    u16* q_asm   = b + off; off += (size_t)NH * S * DQK;
    u16* k_asm   = b + off; off += (size_t)NH * S * DQK;
    u16* vt      = b + off; off += (size_t)NH * DH * S;
    u16* attn_bf = b + off; off += (size_t)S * NH * DH;

    prep_kernel<<<7936, 256, 0, stream>>>(
        x, W_kv_down, W_q_down, W_k_rope, W_k_up, W_v_up, W_q_up, W_q_rope, W_out,
        x_bf,
        WT1, WT1 + (size_t)512 * DM, WT1 + (size_t)1536 * DM,
        WT2, WT2 + (size_t)2048 * DKV,
        WT3, WT3 + (size_t)2048 * DQ, WT4,
        cosT, sinT);

    // G1: x @ [W_kv_down | W_q_down | W_k_rope], N=2560 (20 n-tiles), M=2048 (32 m-tiles)
    gemm_fused_kernel<0><<<640, 256, 0, stream>>>(
        x_bf, WT1, down_kv, down_q, k_asm, cosT, sinT, DM, 640);

    // G2+G3 merged, XCD-swizzled + per-XCD proportional balance
    gemm_g23_kernel<<<1792, 256, 0, stream>>>(
        down_kv, WT2, down_q, WT3, k_asm, vt, q_asm, cosT, sinT);

    attn_mfma_kernel<<<256, 512, 0, stream>>>(q_asm, k_asm, vt, attn_bf);

    // G4: attn_out @ W_out, N=2048 (16 n-tiles), M=2048 (32 m-tiles)
    gemm_fused_kernel<3><<<512, 256, 0, stream>>>(
        attn_bf, WT4, out, nullptr, nullptr, cosT, sinT, DM, 512);
}

// Round 20
// 178.435 us; speedup vs baseline: 1.0149x; 1.0131x over previous
//
#include <hip/hip_runtime.h>
#include <hip/hip_bf16.h>
#include <math.h>

#define S 2048
#define DM 2048
#define NH 16
#define DH 128
#define DR 64
#define DKV 512
#define DQ 1024
#define DQK 192  // DH + DR
#define QSCALE 0.07216878364870323f  // 1/sqrt(192)

typedef __bf16 bf16x8 __attribute__((ext_vector_type(8)));
typedef float f32x4 __attribute__((ext_vector_type(4)));
typedef unsigned short u16;

__device__ inline unsigned int pack2_bf16(float a, float b) {
    __hip_bfloat16 ha = __float2bfloat16(a);
    __hip_bfloat16 hb = __float2bfloat16(b);
    unsigned short ua = *reinterpret_cast<unsigned short*>(&ha);
    unsigned short ub = *reinterpret_cast<unsigned short*>(&hb);
    return (unsigned int)ua | ((unsigned int)ub << 16);
}
__device__ inline u16 f2bf(float v) {
    __hip_bfloat16 hb = __float2bfloat16(v);
    return *reinterpret_cast<u16*>(&hb);
}
__device__ inline void gload_lds16(const void* g, void* l) {
    __builtin_amdgcn_global_load_lds(
        (const __attribute__((address_space(1))) void*)g,
        (__attribute__((address_space(3))) void*)l, 16, 0, 0);
}

// ---------------- fused preprocessing: RoPE table + x->bf16 + 8 weight transposes ----------------
__global__ __launch_bounds__(256) void prep_kernel(
    const float* __restrict__ x,
    const float* __restrict__ W0, const float* __restrict__ W1, const float* __restrict__ W2,
    const float* __restrict__ W3, const float* __restrict__ W4, const float* __restrict__ W5,
    const float* __restrict__ W6, const float* __restrict__ W7,
    u16* __restrict__ x_bf,
    u16* __restrict__ D0, u16* __restrict__ D1, u16* __restrict__ D2, u16* __restrict__ D3,
    u16* __restrict__ D4, u16* __restrict__ D5, u16* __restrict__ D6, u16* __restrict__ D7,
    float* __restrict__ cosT, float* __restrict__ sinT) {
    __shared__ u16 tile[64][65];
    const int b = blockIdx.x;
    if (b < 3584) {
        const float* W; u16* D; int N, K, local;
        if (b < 256)       { W = W0; D = D0; N = 512;  K = 2048; local = b; }
        else if (b < 768)  { W = W1; D = D1; N = 1024; K = 2048; local = b - 256; }
        else if (b < 1280) { W = W2; D = D2; N = 1024; K = 2048; local = b - 768; }
        else if (b < 1536) { W = W3; D = D3; N = 2048; K = 512;  local = b - 1280; }
        else if (b < 1792) { W = W4; D = D4; N = 2048; K = 512;  local = b - 1536; }
        else if (b < 2304) { W = W5; D = D5; N = 2048; K = 1024; local = b - 1792; }
        else if (b < 2560) { W = W6; D = D6; N = 1024; K = 1024; local = b - 2304; }
        else               { W = W7; D = D7; N = 2048; K = 2048; local = b - 2560; }
        const int nt = N / 64;
        const int n0 = (local % nt) * 64;
        const int k0 = (local / nt) * 64;
        const int tx = threadIdx.x & 15;
        const int ty = threadIdx.x >> 4;
#pragma unroll
        for (int rep = 0; rep < 4; ++rep) {
            int kk = rep * 16 + ty;
            float4 v = *reinterpret_cast<const float4*>(&W[(size_t)(k0 + kk) * N + n0 + tx * 4]);
            tile[kk][tx * 4 + 0] = f2bf(v.x);
            tile[kk][tx * 4 + 1] = f2bf(v.y);
            tile[kk][tx * 4 + 2] = f2bf(v.z);
            tile[kk][tx * 4 + 3] = f2bf(v.w);
        }
        __syncthreads();
#pragma unroll
        for (int rep = 0; rep < 4; ++rep) {
            int nn = rep * 16 + ty;
            uint2 w;
            w.x = (unsigned int)tile[tx * 4 + 0][nn] | ((unsigned int)tile[tx * 4 + 1][nn] << 16);
            w.y = (unsigned int)tile[tx * 4 + 2][nn] | ((unsigned int)tile[tx * 4 + 3][nn] << 16);
            *reinterpret_cast<uint2*>(&D[(size_t)(n0 + nn) * K + k0 + tx * 4]) = w;
        }
    } else if (b < 7680) {
        int idx = (b - 3584) * 256 + threadIdx.x;
        float4 v = *reinterpret_cast<const float4*>(&x[(size_t)idx * 4]);
        uint2 w;
        w.x = pack2_bf16(v.x, v.y);
        w.y = pack2_bf16(v.z, v.w);
        *reinterpret_cast<uint2*>(&x_bf[(size_t)idx * 4]) = w;
    } else {
        int idx = (b - 7680) * 256 + threadIdx.x;
        int pos = idx / (DR / 2);
        int j   = idx % (DR / 2);
        float inv = __expf(-((float)(2 * j) / (float)DR) * logf(10000.0f));
        float ang = (float)pos * inv;
        cosT[idx] = cosf(ang);
        sinT[idx] = sinf(ang);
    }
}

// ---------------- bf16 MFMA GEMM core with fused epilogues (R11/R17-verified structure) ----------------
template <int MODE>
__device__ __forceinline__ void gemm_core(
    u16 (*lds)[6144],
    const u16* __restrict__ A, const u16* __restrict__ BT,
    void* __restrict__ P0v, void* __restrict__ P1v, void* __restrict__ P2v,
    const float* __restrict__ cosT, const float* __restrict__ sinT, int K,
    int bm, int bn) {
    const int tid  = threadIdx.x;
    const int wave = tid >> 6;
    const int lane = tid & 63;
    const int c16  = lane & 15;
    const int g    = lane >> 4;
    const int wm = (wave >> 1) * 32;
    const int wn = (wave & 1) * 64;

    f32x4 acc[2][4];
#pragma unroll
    for (int i = 0; i < 2; ++i)
#pragma unroll
        for (int j = 0; j < 4; ++j) acc[i][j] = f32x4{0.f, 0.f, 0.f, 0.f};

    auto stage = [&](int buf, int k0) {
        {
            int L = tid;
            int rp = L >> 3, e = L & 7, x = e ^ (rp & 7);
            int row = 2 * rp + (x >> 2), kc = x & 3;
            gload_lds16(A + (size_t)(bm + row) * K + k0 + kc * 8, &lds[buf][wave * 512]);
        }
#pragma unroll
        for (int r = 0; r < 2; ++r) {
            int L = r * 256 + tid;
            int rp = L >> 3, e = L & 7, x = e ^ (rp & 7);
            int row = 2 * rp + (x >> 2), kc = x & 3;
            gload_lds16(BT + (size_t)(bn + row) * K + k0 + kc * 8,
                        &lds[buf][2048 + (r * 256 + wave * 64) * 8]);
        }
    };

    const int NT = K / 32;
    stage(0, 0);
    __syncthreads();
    int cur = 0;
    for (int t = 0; t < NT; ++t) {
        if (t + 1 < NT) stage(cur ^ 1, (t + 1) * 32);
        bf16x8 af[2], bfr[4];
#pragma unroll
        for (int i = 0; i < 2; ++i) {
            int row  = wm + i * 16 + c16;
            int slot = ((row >> 1) << 3) + ((((row & 1) << 2) + g) ^ ((row >> 1) & 7));
            af[i] = *reinterpret_cast<const bf16x8*>(&lds[cur][slot * 8]);
        }
#pragma unroll
        for (int j = 0; j < 4; ++j) {
            int row  = wn + j * 16 + c16;
            int slot = ((row >> 1) << 3) + ((((row & 1) << 2) + g) ^ ((row >> 1) & 7));
            bfr[j] = *reinterpret_cast<const bf16x8*>(&lds[cur][2048 + slot * 8]);
        }
#pragma unroll
        for (int i = 0; i < 2; ++i)
#pragma unroll
            for (int j = 0; j < 4; ++j)
                acc[i][j] = __builtin_amdgcn_mfma_f32_16x16x32_bf16(af[i], bfr[j], acc[i][j], 0, 0, 0);
        __syncthreads();
        cur ^= 1;
    }

#pragma unroll
    for (int i = 0; i < 2; ++i)
#pragma unroll
        for (int j = 0; j < 4; ++j) {
            const int mrow = bm + wm + i * 16 + g * 4;
            const int col  = bn + wn + j * 16 + c16;
            if constexpr (MODE == 0) {
                if (col < 512) {
                    u16* down_kv = (u16*)P0v;
#pragma unroll
                    for (int r = 0; r < 4; ++r)
                        down_kv[(size_t)(mrow + r) * DKV + col] = f2bf(acc[i][j][r]);
                } else if (col < 1536) {
                    u16* down_q = (u16*)P1v;
#pragma unroll
                    for (int r = 0; r < 4; ++r)
                        down_q[(size_t)(mrow + r) * DQ + (col - 512)] = f2bf(acc[i][j][r]);
                } else {
                    u16* k_asm = (u16*)P2v;
                    const int cc = col - 1536, h = cc >> 6, rr = cc & 63, jj = rr >> 1;
#pragma unroll
                    for (int r = 0; r < 4; ++r) {
                        int pos = mrow + r;
                        float self = acc[i][j][r];
                        float vp   = __shfl_xor(self, 1);
                        float c = cosT[pos * (DR / 2) + jj];
                        float s = sinT[pos * (DR / 2) + jj];
                        float val = (rr & 1) ? (vp * s + self * c) : (self * c - vp * s);
                        k_asm[((size_t)h * S + pos) * DQK + DH + rr] = f2bf(val);
                    }
                }
            } else if constexpr (MODE == 1) {
                if (col < 2048) {
                    u16* k_asm = (u16*)P0v;
                    const int h = col >> 7, d = col & 127;
#pragma unroll
                    for (int r = 0; r < 4; ++r)
                        k_asm[((size_t)h * S + mrow + r) * DQK + d] = f2bf(acc[i][j][r]);
                } else {
                    u16* vt = (u16*)P1v;
                    const int cc = col - 2048, h = cc >> 7, d = cc & 127;
                    uint2 w;
                    w.x = pack2_bf16(acc[i][j][0], acc[i][j][1]);
                    w.y = pack2_bf16(acc[i][j][2], acc[i][j][3]);
                    *reinterpret_cast<uint2*>(&vt[((size_t)h * DH + d) * S + mrow]) = w;
                }
            } else if constexpr (MODE == 2) {
                u16* q_asm = (u16*)P0v;
                if (col < 2048) {
                    const int h = col >> 7, d = col & 127;
#pragma unroll
                    for (int r = 0; r < 4; ++r)
                        q_asm[((size_t)h * S + mrow + r) * DQK + d] = f2bf(acc[i][j][r] * QSCALE);
                } else {
                    const int cc = col - 2048, h = cc >> 6, rr = cc & 63, jj = rr >> 1;
#pragma unroll
                    for (int r = 0; r < 4; ++r) {
                        int pos = mrow + r;
                        float self = acc[i][j][r];
                        float vp   = __shfl_xor(self, 1);
                        float c = cosT[pos * (DR / 2) + jj];
                        float s = sinT[pos * (DR / 2) + jj];
                        float val = (rr & 1) ? (vp * s + self * c) : (self * c - vp * s);
                        q_asm[((size_t)h * S + pos) * DQK + DH + rr] = f2bf(val * QSCALE);
                    }
                }
            } else {  // MODE 3
                float* outp = (float*)P0v;
#pragma unroll
                for (int r = 0; r < 4; ++r)
                    outp[(size_t)(mrow + r) * DM + col] = acc[i][j][r];
            }
        }
}

// XCD-aware swizzle (T1): 1-D grid, xcd = wgid&7 gets a contiguous chunk of the
// m-fastest linear order -> per-XCD B-panel strip L2-resident. Grids %8==0 -> bijective.
template <int MODE>
__global__ __launch_bounds__(256) void gemm_fused_kernel(
    const u16* __restrict__ A, const u16* __restrict__ BT,
    void* __restrict__ P0v, void* __restrict__ P1v, void* __restrict__ P2v,
    const float* __restrict__ cosT, const float* __restrict__ sinT, int K, int nwg) {
    __shared__ u16 lds[2][6144];
    const int wgid = blockIdx.x;
    const int orig = (wgid & 7) * (nwg >> 3) + (wgid >> 3);
    const int bm = (orig & 31) * 64;   // m fastest (32 m-tiles)
    const int bn = (orig >> 5) * 128;
    gemm_core<MODE>(lds, A, BT, P0v, P1v, P2v, cosT, sinT, K, bm, bn);
}

// G2 (1024 tiles) + G3 (768 tiles) merged, XCD-swizzled with PROPORTIONAL per-XCD split:
// each XCD gets 128 G2 blocks (4 n-tiles x 32 m) + 96 G3 blocks (3 n-tiles x 32 m).
__global__ __launch_bounds__(256) void gemm_g23_kernel(
    const u16* __restrict__ down_kv, const u16* __restrict__ WT2,
    const u16* __restrict__ down_q,  const u16* __restrict__ WT3,
    u16* __restrict__ k_asm, u16* __restrict__ vt, u16* __restrict__ q_asm,
    const float* __restrict__ cosT, const float* __restrict__ sinT) {
    __shared__ u16 lds[2][6144];
    const int wgid  = blockIdx.x;
    const int xcd   = wgid & 7;
    const int local = wgid >> 3;  // 0..223
    if (local < 128) {
        const int bn = (xcd * 4 + (local >> 5)) * 128;
        const int bm = (local & 31) * 64;
        gemm_core<1>(lds, down_kv, WT2, k_asm, vt, nullptr, cosT, sinT, DKV, bm, bn);
    } else {
        const int l  = local - 128;
        const int bn = (xcd * 3 + (l >> 5)) * 128;
        const int bm = (l & 31) * 64;
        gemm_core<2>(lds, down_q, WT3, q_asm, nullptr, nullptr, cosT, sinT, DQ, bm, bn);
    }
}

// ---------------- MFMA flash attention v10 (R14/R17-verified, 54us): 8 waves, intra-block split-KV ----------------
__global__ __launch_bounds__(512) void attn_mfma_kernel(const u16* __restrict__ q,   // (NH,S,192) pre-scaled
                                                        const u16* __restrict__ k,   // (NH,S,192)
                                                        const u16* __restrict__ vt,  // (NH,DH,S)
                                                        u16* __restrict__ outp) {    // (S, NH*DH) bf16
    const int wgid = blockIdx.x;        // 0..255
    const int xcd  = wgid & 7;
    const int i    = wgid >> 3;         // 0..31 per xcd
    const int h    = xcd * 2 + (i & 1); // head pinned to XCD
    const int pr   = i >> 1;            // 0..15
    const int qtA  = 31 - pr;
    const int qtB  = pr;

    const int tid  = threadIdx.x;       // 0..511
    const int wave = tid >> 6;          // 0..7
    const int grp  = wave >> 2;         // 0: even tiles, 1: odd tiles
    const int w4   = wave & 3;          // q-row group within grp
    const int lane = tid & 63;
    const int col  = lane & 15;
    const int g    = lane >> 4;

    __shared__ __align__(16) char arena[92160];
    u16* KtG = (u16*)(arena + (grp ? 24576 : 0));
    u16* VtG = (u16*)(arena + 49152 + (grp ? 16384 : 0));
    u16* p_my = (u16*)(arena + 81920 + wave * 1024);
    float2* ml = (float2*)(arena + 90112);
    f32x4* cmb = (f32x4*)(arena);

    const int r7  = col & 7;
    const int pv7 = (col >> 1) & 7;
    const int pvb = (col & 1) << 2;

    auto stage_pair = [&](int buf, int j0E) {
#pragma unroll
        for (int c = 0; c < 5; ++c) {
            int idx = wave + c * 8;
            if (idx < 12) {
                int L = idx * 64 + lane;
                int row = L / 24, rem = L - row * 24;
                int ch  = ((rem >> 3) << 3) + ((rem & 7) ^ (row & 7));
                gload_lds16(k + ((size_t)h * S + j0E + row) * DQK + ch * 8,
                            (u16*)(arena) + buf * 6144 + idx * 512);
            } else if (idx < 20) {
                int s2 = idx - 12;
                int L = s2 * 64 + lane;
                int rp = L >> 3, x = (L & 7) ^ (rp & 7);
                int d  = 2 * rp + (x >> 2), kc = x & 3;
                gload_lds16(vt + ((size_t)h * DH + d) * S + j0E + kc * 8,
                            (u16*)(arena + 49152) + buf * 4096 + s2 * 512);
            } else if (idx < 32) {
                int s2 = idx - 20;
                int L = s2 * 64 + lane;
                int row = L / 24, rem = L - row * 24;
                int ch  = ((rem >> 3) << 3) + ((rem & 7) ^ (row & 7));
                gload_lds16(k + ((size_t)h * S + j0E + 32 + row) * DQK + ch * 8,
                            (u16*)(arena + 24576) + buf * 6144 + s2 * 512);
            } else {
                int s2 = idx - 32;
                int L = s2 * 64 + lane;
                int rp = L >> 3, x = (L & 7) ^ (rp & 7);
                int d  = 2 * rp + (x >> 2), kc = x & 3;
                gload_lds16(vt + ((size_t)h * DH + d) * S + j0E + 32 + kc * 8,
                            (u16*)(arena + 65536) + buf * 4096 + s2 * 512);
            }
        }
    };

    auto phase = [&](int qt) {
        const int q0 = qt * 64;
        const int qw = q0 + w4 * 16;
        const int I  = qt + 1;

        bf16x8 qf[6];
        const u16* qbase = q + ((size_t)h * S + qw + col) * DQK + g * 8;
#pragma unroll
        for (int c = 0; c < 6; ++c) qf[c] = *reinterpret_cast<const bf16x8*>(qbase + c * 32);

        f32x4 acc[8];
#pragma unroll
        for (int c = 0; c < 8; ++c) acc[c] = f32x4{0.f, 0.f, 0.f, 0.f};
        float m_run = -1e30f, l_run = 0.f;

        stage_pair(0, 0);
        __syncthreads();
        for (int tp = 0; tp < I; ++tp) {
            if (tp + 1 < I) stage_pair((tp + 1) & 1, (tp + 1) * 64);
            const int buf = tp & 1;
            const int j0  = tp * 64 + grp * 32;
            const u16* Kc = KtG + buf * 6144;
            const u16* Vc = VtG + buf * 4096;

            f32x4 st[2];
            st[0] = f32x4{0.f, 0.f, 0.f, 0.f};
            st[1] = f32x4{0.f, 0.f, 0.f, 0.f};
#pragma unroll
            for (int tt = 0; tt < 2; ++tt) {
                int rb = (16 * tt + col) * 24;
#pragma unroll
                for (int c = 0; c < 6; ++c) {
                    int ch   = g + 4 * c;
                    int slot = rb + ((ch >> 3) << 3) + ((ch & 7) ^ r7);
                    bf16x8 kf = *reinterpret_cast<const bf16x8*>(Kc + slot * 8);
                    st[tt] = __builtin_amdgcn_mfma_f32_16x16x32_bf16(kf, qf[c], st[tt], 0, 0, 0);
                }
            }
#pragma unroll
            for (int tt = 0; tt < 2; ++tt) {
                if (j0 + 16 * tt + 15 > qw) {
#pragma unroll
                    for (int r = 0; r < 4; ++r) {
                        int key = j0 + 16 * tt + 4 * g + r;
                        st[tt][r] = (key > qw + col) ? -1e30f : st[tt][r];
                    }
                }
            }
            float tmax = fmaxf(fmaxf(fmaxf(st[0][0], st[0][1]), fmaxf(st[0][2], st[0][3])),
                               fmaxf(fmaxf(st[1][0], st[1][1]), fmaxf(st[1][2], st[1][3])));
            tmax = fmaxf(tmax, __shfl_xor(tmax, 16));
            tmax = fmaxf(tmax, __shfl_xor(tmax, 32));
            float m_new;
            if (__all(tmax - m_run <= 8.0f)) {
                m_new = m_run;
            } else {
                m_new = fmaxf(m_run, tmax);
                float r_scale = __expf(m_run - m_new);
                l_run *= r_scale;
#pragma unroll
                for (int c = 0; c < 8; ++c) {
                    acc[c][0] *= r_scale; acc[c][1] *= r_scale;
                    acc[c][2] *= r_scale; acc[c][3] *= r_scale;
                }
                m_run = m_new;
            }
            float m_sub = (m_new <= -1e29f) ? 0.f : m_new;
            float p[8];
            float psum = 0.f;
#pragma unroll
            for (int tt = 0; tt < 2; ++tt)
#pragma unroll
                for (int r = 0; r < 4; ++r) {
                    float pv = __expf(st[tt][r] - m_sub);
                    p[tt * 4 + r] = pv;
                    psum += pv;
                }
            psum += __shfl_xor(psum, 16);
            psum += __shfl_xor(psum, 32);
            l_run += psum;
#pragma unroll
            for (int tt = 0; tt < 2; ++tt) {
                uint2 w;
                w.x = pack2_bf16(p[tt * 4 + 0], p[tt * 4 + 1]);
                w.y = pack2_bf16(p[tt * 4 + 2], p[tt * 4 + 3]);
                int ch   = 2 * tt + (g >> 1);
                int slot = ((col >> 1) << 3) + ((pvb + ch) ^ pv7);
                *reinterpret_cast<uint2*>(p_my + slot * 8 + (g & 1) * 4) = w;
            }
            {
                int slot = ((col >> 1) << 3) + ((pvb + g) ^ pv7);
                bf16x8 pf = *reinterpret_cast<const bf16x8*>(p_my + slot * 8);
#pragma unroll
                for (int c = 0; c < 8; ++c) {
                    int d  = 16 * c + col;
                    int vs = ((d >> 1) << 3) + ((pvb + g) ^ pv7);
                    bf16x8 vf = *reinterpret_cast<const bf16x8*>(Vc + vs * 8);
                    acc[c] = __builtin_amdgcn_mfma_f32_16x16x32_bf16(vf, pf, acc[c], 0, 0, 0);
                }
            }
            __syncthreads();
        }

        if (grp == 1) {
#pragma unroll
            for (int c = 0; c < 8; ++c) cmb[(w4 * 8 + c) * 64 + lane] = acc[c];
            ml[w4 * 64 + lane] = make_float2(m_run, l_run);
        }
        __syncthreads();
        if (grp == 0) {
            float2 mlB = ml[w4 * 64 + lane];
            float m = fmaxf(m_run, mlB.x);
            float sA = __expf(m_run - m);
            float sB = __expf(mlB.x - m);
            float l  = l_run * sA + mlB.y * sB;
            float inv_l = 1.0f / l;
#pragma unroll
            for (int c = 0; c < 8; ++c) {
                f32x4 aB = cmb[(w4 * 8 + c) * 64 + lane];
#pragma unroll
                for (int r = 0; r < 4; ++r) {
                    float v = (acc[c][r] * sA + aB[r] * sB) * inv_l;
                    outp[(size_t)(qw + col) * (NH * DH) + h * DH + 16 * c + 4 * g + r] = f2bf(v);
                }
            }
        }
        __syncthreads();
    };

    phase(qtA);
    phase(qtB);
}

// ---------------- launch ----------------
extern "C" void kernel_launch(void* const* d_in, const int* in_sizes, int n_in,
                              void* d_out, int out_size, void* d_ws, size_t ws_size,
                              hipStream_t stream) {
    const float* x         = (const float*)d_in[0];
    const float* W_kv_down = (const float*)d_in[2];
    const float* W_k_up    = (const float*)d_in[3];
    const float* W_v_up    = (const float*)d_in[4];
    const float* W_q_down  = (const float*)d_in[5];
    const float* W_q_up    = (const float*)d_in[6];
    const float* W_q_rope  = (const float*)d_in[7];
    const float* W_k_rope  = (const float*)d_in[8];
    const float* W_out     = (const float*)d_in[9];
    float* out = (float*)d_out;

    float* w = (float*)d_ws;
    float* cosT = w;
    float* sinT = w + (size_t)S * (DR / 2);
    u16* b = (u16*)(w + 2 * (size_t)S * (DR / 2));
    size_t off = 0;
    u16* x_bf    = b + off; off += (size_t)S * DM;
    u16* WT1     = b + off; off += (size_t)2560 * DM;
    u16* WT2     = b + off; off += (size_t)4096 * DKV;
    u16* WT3     = b + off; off += (size_t)3072 * DQ;
    u16* WT4     = b + off; off += (size_t)DM * DM;
    u16* down_kv = b + off; off += (size_t)S * DKV;
    u16* down_q  = b + off; off += (size_t)S * DQ;
    u16* q_asm   = b + off; off += (size_t)NH * S * DQK;
    u16* k_asm   = b + off; off += (size_t)NH * S * DQK;
    u16* vt      = b + off; off += (size_t)NH * DH * S;
    u16* attn_bf = b + off; off += (size_t)S * NH * DH;

    prep_kernel<<<7936, 256, 0, stream>>>(
        x, W_kv_down, W_q_down, W_k_rope, W_k_up, W_v_up, W_q_up, W_q_rope, W_out,
        x_bf,
        WT1, WT1 + (size_t)512 * DM, WT1 + (size_t)1536 * DM,
        WT2, WT2 + (size_t)2048 * DKV,
        WT3, WT3 + (size_t)2048 * DQ, WT4,
        cosT, sinT);

    // G1: x @ [W_kv_down | W_q_down | W_k_rope], N=2560 (20 n-tiles), M=2048 (32 m-tiles)
    gemm_fused_kernel<0><<<640, 256, 0, stream>>>(
        x_bf, WT1, down_kv, down_q, k_asm, cosT, sinT, DM, 640);

    // G2+G3 merged, XCD-swizzled + per-XCD proportional balance
    gemm_g23_kernel<<<1792, 256, 0, stream>>>(
        down_kv, WT2, down_q, WT3, k_asm, vt, q_asm, cosT, sinT);

    attn_mfma_kernel<<<256, 512, 0, stream>>>(q_asm, k_asm, vt, attn_bf);

    // G4: attn_out @ W_out, N=2048 (16 n-tiles), M=2048 (32 m-tiles)
    gemm_fused_kernel<3><<<512, 256, 0, stream>>>(
        attn_bf, WT4, out, nullptr, nullptr, cosT, sinT, DM, 512);
}